// Round 1
// baseline (5663.351 us; speedup 1.0000x reference)
//
#include <hip/hip_runtime.h>

#define N_NODES 100000
#define N_EDGES 3200000
#define IN_DIM 64
#define HID_DIM 128
#define OUT_DIM 2

// ---------------------------------------------------------------------------
// K2: in-degree histogram (self-loop folded in later as +1)
__global__ __launch_bounds__(256) void deg_kernel(const int* __restrict__ dst,
                                                  float* __restrict__ deg) {
    int e = blockIdx.x * 256 + threadIdx.x;
    if (e < N_EDGES) atomicAdd(&deg[dst[e]], 1.0f);
}

// K3: dinv = rsqrt(deg + 1)  (in place; +1 is the self-loop)
__global__ __launch_bounds__(256) void dinv_kernel(float* __restrict__ deg) {
    int i = blockIdx.x * 256 + threadIdx.x;
    if (i < N_NODES) deg[i] = rsqrtf(deg[i] + 1.0f);
}

// K4: g = (x @ W_gcn) * dinv[row].  W (64x128 = 32KB) staged in LDS.
// 8 nodes per 256-thread block; thread = (node_local, col_quad).
#define GEMM_NPB 8
__global__ __launch_bounds__(256) void gemm_kernel(const float* __restrict__ x,
                                                   const float* __restrict__ W,
                                                   const float* __restrict__ dinv,
                                                   float* __restrict__ g) {
    __shared__ float4 Ws[IN_DIM * HID_DIM / 4];       // 2048 float4 = 32 KB
    __shared__ float  xs[GEMM_NPB * IN_DIM];          // 512 floats = 2 KB
    const int tid = threadIdx.x;

    const float4* W4 = (const float4*)W;
    #pragma unroll
    for (int i = tid; i < IN_DIM * HID_DIM / 4; i += 256) Ws[i] = W4[i];

    const int node0 = blockIdx.x * GEMM_NPB;          // 12500 * 8 = 100000 exact
    const float4* x4 = (const float4*)(x + (size_t)node0 * IN_DIM);
    for (int i = tid; i < GEMM_NPB * IN_DIM / 4; i += 256) ((float4*)xs)[i] = x4[i];
    __syncthreads();

    const int jq = tid & 31;    // col quad: cols 4*jq .. 4*jq+3
    const int nl = tid >> 5;    // local node 0..7
    const float* xrow = xs + nl * IN_DIM;

    float4 acc = {0.f, 0.f, 0.f, 0.f};
    #pragma unroll
    for (int k = 0; k < IN_DIM; ++k) {
        const float  xv = xrow[k];
        const float4 wv = Ws[k * 32 + jq];
        acc.x += xv * wv.x; acc.y += xv * wv.y;
        acc.z += xv * wv.z; acc.w += xv * wv.w;
    }
    const int node = node0 + nl;
    const float dv = dinv[node];
    acc.x *= dv; acc.y *= dv; acc.z *= dv; acc.w *= dv;
    ((float4*)g)[(size_t)node * 32 + jq] = acc;
}

// K5: edge scatter — 32 lanes per edge, float4 gather of g[src], 4 atomics/lane.
__global__ __launch_bounds__(256) void scatter_kernel(const int* __restrict__ ei,
                                                      const float* __restrict__ g,
                                                      float* __restrict__ agg) {
    const int t    = blockIdx.x * 256 + threadIdx.x;   // < 102.4M, fits int32
    const int e    = t >> 5;
    const int lane = t & 31;
    if (e >= N_EDGES) return;
    const int s = ei[e];
    const int d = ei[N_EDGES + e];
    const float4 val = ((const float4*)g)[(size_t)s * 32 + lane];
    float* dp = agg + (size_t)d * HID_DIM + lane * 4;
    atomicAdd(dp + 0, val.x);
    atomicAdd(dp + 1, val.y);
    atomicAdd(dp + 2, val.z);
    atomicAdd(dp + 3, val.w);
}

// K6: out = relu(dinv*(agg + g) + b_gcn) @ W_lin + b_lin.  One wave per node.
__global__ __launch_bounds__(256) void final_kernel(const float* __restrict__ agg,
                                                    const float* __restrict__ g,
                                                    const float* __restrict__ dinv,
                                                    const float* __restrict__ b_gcn,
                                                    const float* __restrict__ W_lin,
                                                    const float* __restrict__ b_lin,
                                                    float* __restrict__ out) {
    const int n    = (blockIdx.x * 256 + threadIdx.x) >> 6;
    const int lane = threadIdx.x & 63;
    if (n >= N_NODES) return;
    const float dv = dinv[n];
    float o0 = 0.f, o1 = 0.f;
    #pragma unroll
    for (int r = 0; r < 2; ++r) {
        const int c = lane + r * 64;
        float v = dv * (agg[(size_t)n * HID_DIM + c] + g[(size_t)n * HID_DIM + c]) + b_gcn[c];
        v = fmaxf(v, 0.f);
        o0 += v * W_lin[c * 2 + 0];
        o1 += v * W_lin[c * 2 + 1];
    }
    #pragma unroll
    for (int off = 32; off > 0; off >>= 1) {
        o0 += __shfl_down(o0, off, 64);
        o1 += __shfl_down(o1, off, 64);
    }
    if (lane == 0) {
        out[n * 2 + 0] = o0 + b_lin[0];
        out[n * 2 + 1] = o1 + b_lin[1];
    }
}

extern "C" void kernel_launch(void* const* d_in, const int* in_sizes, int n_in,
                              void* d_out, int out_size, void* d_ws, size_t ws_size,
                              hipStream_t stream) {
    const float* x     = (const float*)d_in[0];
    const int*   ei    = (const int*)  d_in[1];   // [2, E]: row 0 = src, row 1 = dst
    const float* W_gcn = (const float*)d_in[2];
    const float* b_gcn = (const float*)d_in[3];
    const float* W_lin = (const float*)d_in[4];
    const float* b_lin = (const float*)d_in[5];
    float* out = (float*)d_out;

    // workspace layout: g [N*H] | agg [N*H] | deg/dinv [N]
    float* g   = (float*)d_ws;
    float* agg = g + (size_t)N_NODES * HID_DIM;
    float* deg = agg + (size_t)N_NODES * HID_DIM;

    // zero agg + deg in one shot (contiguous)
    hipMemsetAsync(agg, 0, ((size_t)N_NODES * HID_DIM + N_NODES) * sizeof(float), stream);

    deg_kernel<<<(N_EDGES + 255) / 256, 256, 0, stream>>>(ei + N_EDGES, deg);
    dinv_kernel<<<(N_NODES + 255) / 256, 256, 0, stream>>>(deg);
    gemm_kernel<<<N_NODES / GEMM_NPB, 256, 0, stream>>>(x, W_gcn, deg, g);
    scatter_kernel<<<N_EDGES / 8, 256, 0, stream>>>(ei, g, agg);  // 32 lanes/edge
    final_kernel<<<(N_NODES + 3) / 4, 256, 0, stream>>>(agg, g, deg, b_gcn, W_lin, b_lin, out);
}

// Round 2
// 748.746 us; speedup vs baseline: 7.5638x; 7.5638x over previous
//
#include <hip/hip_runtime.h>

#define N_NODES 100000
#define N_EDGES 3200000
#define IN_DIM 64
#define HID_DIM 128
#define OUT_DIM 2
#define NB_SCAN 391   // ceil(N_NODES / 256)

// ---------------------------------------------------------------------------
// K1: int in-degree histogram (real edges only; self-loop folded in as +1 later)
__global__ __launch_bounds__(256) void deg_count_kernel(const int* __restrict__ dst,
                                                        int* __restrict__ degi) {
    int e = blockIdx.x * 256 + threadIdx.x;
    if (e < N_EDGES) atomicAdd(&degi[dst[e]], 1);
}

// K2: per-256-block sums of degi -> partial[NB_SCAN]
__global__ __launch_bounds__(256) void blocksum_kernel(const int* __restrict__ degi,
                                                       int* __restrict__ partial) {
    __shared__ int s[256];
    const int tid = threadIdx.x;
    const int i = blockIdx.x * 256 + tid;
    s[tid] = (i < N_NODES) ? degi[i] : 0;
    __syncthreads();
    #pragma unroll
    for (int off = 128; off > 0; off >>= 1) {
        if (tid < off) s[tid] += s[tid + off];
        __syncthreads();
    }
    if (tid == 0) partial[blockIdx.x] = s[0];
}

// K3: exclusive scan of partial[NB_SCAN] in one 512-thread block
__global__ __launch_bounds__(512) void scan_partial_kernel(int* __restrict__ partial) {
    __shared__ int s[512];
    const int tid = threadIdx.x;
    const int v = (tid < NB_SCAN) ? partial[tid] : 0;
    s[tid] = v;
    __syncthreads();
    for (int off = 1; off < 512; off <<= 1) {
        int t = (tid >= off) ? s[tid - off] : 0;
        __syncthreads();
        s[tid] += t;
        __syncthreads();
    }
    if (tid < NB_SCAN) partial[tid] = s[tid] - v;   // exclusive
}

// K4: local inclusive scan + block offset -> row_ptr, cursor; also dinv
__global__ __launch_bounds__(256) void writeptr_kernel(const int* __restrict__ degi,
                                                       const int* __restrict__ partial,
                                                       int* __restrict__ row_ptr,
                                                       int* __restrict__ cursor,
                                                       float* __restrict__ dinv) {
    __shared__ int s[256];
    const int tid = threadIdx.x;
    const int i = blockIdx.x * 256 + tid;
    const int v = (i < N_NODES) ? degi[i] : 0;
    s[tid] = v;
    __syncthreads();
    for (int off = 1; off < 256; off <<= 1) {
        int t = (tid >= off) ? s[tid - off] : 0;
        __syncthreads();
        s[tid] += t;
        __syncthreads();
    }
    if (i < N_NODES) {
        const int start = partial[blockIdx.x] + s[tid] - v;   // exclusive global
        row_ptr[i] = start;
        cursor[i]  = start;
        dinv[i]    = rsqrtf((float)v + 1.0f);
        if (i == N_NODES - 1) row_ptr[N_NODES] = start + v;
    }
}

// K5: CSR fill — col[pos] = src, pos from per-dst cursor
__global__ __launch_bounds__(256) void fill_kernel(const int* __restrict__ ei,
                                                   int* __restrict__ cursor,
                                                   int* __restrict__ col) {
    int e = blockIdx.x * 256 + threadIdx.x;
    if (e < N_EDGES) {
        const int s = ei[e];
        const int d = ei[N_EDGES + e];
        const int pos = atomicAdd(&cursor[d], 1);
        col[pos] = s;
    }
}

// K6: g = (x @ W_gcn) * dinv[row].  W (64x128 = 32KB) staged in LDS.
#define GEMM_NPB 8
__global__ __launch_bounds__(256) void gemm_kernel(const float* __restrict__ x,
                                                   const float* __restrict__ W,
                                                   const float* __restrict__ dinv,
                                                   float* __restrict__ g) {
    __shared__ float4 Ws[IN_DIM * HID_DIM / 4];       // 32 KB
    __shared__ float  xs[GEMM_NPB * IN_DIM];          // 2 KB
    const int tid = threadIdx.x;

    const float4* W4 = (const float4*)W;
    #pragma unroll
    for (int i = tid; i < IN_DIM * HID_DIM / 4; i += 256) Ws[i] = W4[i];

    const int node0 = blockIdx.x * GEMM_NPB;
    const float4* x4 = (const float4*)(x + (size_t)node0 * IN_DIM);
    for (int i = tid; i < GEMM_NPB * IN_DIM / 4; i += 256) ((float4*)xs)[i] = x4[i];
    __syncthreads();

    const int jq = tid & 31;
    const int nl = tid >> 5;
    const float* xrow = xs + nl * IN_DIM;

    float4 acc = {0.f, 0.f, 0.f, 0.f};
    #pragma unroll
    for (int k = 0; k < IN_DIM; ++k) {
        const float  xv = xrow[k];
        const float4 wv = Ws[k * 32 + jq];
        acc.x += xv * wv.x; acc.y += xv * wv.y;
        acc.z += xv * wv.z; acc.w += xv * wv.w;
    }
    const int node = node0 + nl;
    const float dv = dinv[node];
    acc.x *= dv; acc.y *= dv; acc.z *= dv; acc.w *= dv;
    ((float4*)g)[(size_t)node * 32 + jq] = acc;
}

// K7: fused gather + epilogue. 32 lanes per node; lane l holds float4 cols 4l..4l+3.
// acc = g[n] (self) + sum_{s in CSR[n]} g[s];  v = relu(acc*dinv[n] + b_gcn);
// out[n] = v @ W_lin + b_lin  (reduced across the 32-lane group).
__global__ __launch_bounds__(256) void gather_kernel(const int* __restrict__ row_ptr,
                                                     const int* __restrict__ col,
                                                     const float* __restrict__ g,
                                                     const float* __restrict__ dinv,
                                                     const float* __restrict__ b_gcn,
                                                     const float* __restrict__ W_lin,
                                                     const float* __restrict__ b_lin,
                                                     float* __restrict__ out) {
    const int t    = blockIdx.x * 256 + threadIdx.x;
    const int n    = t >> 5;
    const int lane = t & 31;
    if (n >= N_NODES) return;

    const float4* g4 = (const float4*)g;
    float4 acc = g4[(size_t)n * 32 + lane];           // self-loop message
    const int beg = row_ptr[n];
    const int end = row_ptr[n + 1];

    for (int k = beg; k < end; k += 32) {
        const int m = end - k;
        const int sc = (lane < m) ? col[k + lane] : 0;   // 32 cols, coalesced
        const int lim = m < 32 ? m : 32;
        for (int j = 0; j < lim; ++j) {
            const int s = __shfl(sc, j, 32);
            const float4 v = g4[(size_t)s * 32 + lane];  // 512B coalesced per group
            acc.x += v.x; acc.y += v.y; acc.z += v.z; acc.w += v.w;
        }
    }

    const float dv = dinv[n];
    const float4 bg = ((const float4*)b_gcn)[lane];
    float4 v;
    v.x = fmaxf(acc.x * dv + bg.x, 0.f);
    v.y = fmaxf(acc.y * dv + bg.y, 0.f);
    v.z = fmaxf(acc.z * dv + bg.z, 0.f);
    v.w = fmaxf(acc.w * dv + bg.w, 0.f);

    const int c = lane * 4;
    float o0 = v.x * W_lin[(c+0)*2] + v.y * W_lin[(c+1)*2] + v.z * W_lin[(c+2)*2] + v.w * W_lin[(c+3)*2];
    float o1 = v.x * W_lin[(c+0)*2+1] + v.y * W_lin[(c+1)*2+1] + v.z * W_lin[(c+2)*2+1] + v.w * W_lin[(c+3)*2+1];

    #pragma unroll
    for (int off = 16; off > 0; off >>= 1) {
        o0 += __shfl_down(o0, off, 32);
        o1 += __shfl_down(o1, off, 32);
    }
    if (lane == 0) {
        out[(size_t)n * 2 + 0] = o0 + b_lin[0];
        out[(size_t)n * 2 + 1] = o1 + b_lin[1];
    }
}

extern "C" void kernel_launch(void* const* d_in, const int* in_sizes, int n_in,
                              void* d_out, int out_size, void* d_ws, size_t ws_size,
                              hipStream_t stream) {
    const float* x     = (const float*)d_in[0];
    const int*   ei    = (const int*)  d_in[1];   // [2, E]: row 0 = src, row 1 = dst
    const float* W_gcn = (const float*)d_in[2];
    const float* b_gcn = (const float*)d_in[3];
    const float* W_lin = (const float*)d_in[4];
    const float* b_lin = (const float*)d_in[5];
    float* out = (float*)d_out;

    // workspace layout (all 4-byte elems, g first for float4 alignment):
    // g[N*128] | col[E] | row_ptr[N+1] | cursor[N] | degi[N] | dinv[N] | partial[512]
    float* g       = (float*)d_ws;
    int*   col     = (int*)(g + (size_t)N_NODES * HID_DIM);
    int*   row_ptr = col + N_EDGES;
    int*   cursor  = row_ptr + (N_NODES + 1);
    int*   degi    = cursor + N_NODES;
    float* dinv    = (float*)(degi + N_NODES);
    int*   partial = (int*)(dinv + N_NODES);

    hipMemsetAsync(degi, 0, N_NODES * sizeof(int), stream);

    deg_count_kernel<<<(N_EDGES + 255) / 256, 256, 0, stream>>>(ei + N_EDGES, degi);
    blocksum_kernel<<<NB_SCAN, 256, 0, stream>>>(degi, partial);
    scan_partial_kernel<<<1, 512, 0, stream>>>(partial);
    writeptr_kernel<<<NB_SCAN, 256, 0, stream>>>(degi, partial, row_ptr, cursor, dinv);
    gemm_kernel<<<N_NODES / GEMM_NPB, 256, 0, stream>>>(x, W_gcn, dinv, g);
    fill_kernel<<<(N_EDGES + 255) / 256, 256, 0, stream>>>(ei, cursor, col);
    gather_kernel<<<(N_NODES * 32 + 255) / 256, 256, 0, stream>>>(
        row_ptr, col, g, dinv, b_gcn, W_lin, b_lin, out);
}